// Round 1
// baseline (359.864 us; speedup 1.0000x reference)
//
#include <hip/hip_runtime.h>
#include <hip/hip_fp16.h>
#include <stdint.h>

#define NN 4096      // nodes
#define FF 512       // in features
#define DD 64        // head dim
#define HH 4         // heads
#define MM 2         // metapaths
#define LOG2E 1.44269504088896340736f
#define ALPHA_LR 0.2f

typedef float f32x4 __attribute__((ext_vector_type(4)));
typedef _Float16 f16x8 __attribute__((ext_vector_type(8)));

union H4 { ushort4 u; _Float16 h[4]; };

__device__ inline float fast_exp2(float x) {
#if __has_builtin(__builtin_amdgcn_exp2f)
    return __builtin_amdgcn_exp2f(x);
#else
    return exp2f(x);
#endif
}
__device__ inline float fast_rcp(float x) {
#if __has_builtin(__builtin_amdgcn_rcpf)
    return __builtin_amdgcn_rcpf(x);
#else
    return 1.0f / x;
#endif
}
__device__ inline f32x4 mfma16(f16x8 a, f16x8 b, f32x4 c) {
    return __builtin_amdgcn_mfma_f32_16x16x32_f16(a, b, c, 0, 0, 0);
}

// ---- x [N,F] fp32 -> f16 ----
__global__ __launch_bounds__(256) void k_conv_x(const float* __restrict__ x,
                                                _Float16* __restrict__ xh) {
    int t = blockIdx.x * 256 + threadIdx.x;   // N*F/4 threads
    float4 v = ((const float4*)x)[t];
    H4 o;
    o.h[0] = (_Float16)v.x; o.h[1] = (_Float16)v.y;
    o.h[2] = (_Float16)v.z; o.h[3] = (_Float16)v.w;
    ((ushort4*)xh)[t] = o.u;
}

// ---- W [H][F][D] fp32 -> W_T f16 [H*D][F] ----
__global__ __launch_bounds__(256) void k_conv_w(const float* __restrict__ W,
                                                _Float16* __restrict__ wt) {
    int t = blockIdx.x * 256 + threadIdx.x;   // 256*512 threads
    int c = t >> 9, f = t & 511;
    int h = c >> 6, d = c & 63;
    wt[t] = (_Float16)W[(h * FF + f) * DD + d];
}

// ---- adj int32 {0,1} -> bitmask [m][i][128 words] ----
__global__ __launch_bounds__(256) void k_pack(const int* __restrict__ adj,
                                              uint32_t* __restrict__ bits) {
    long long e = (long long)blockIdx.x * 256 + threadIdx.x;
    int v = adj[e];
    unsigned long long m = __ballot(v != 0);
    if ((threadIdx.x & 63) == 0)
        ((unsigned long long*)bits)[e >> 6] = m;
}

// ---- Wh = x @ W[h], stored transposed f16: whT[h*64+d][n] ----
__global__ __launch_bounds__(256) void k_wh(const _Float16* __restrict__ xh,
                                            const _Float16* __restrict__ wt,
                                            _Float16* __restrict__ whT) {
    const int h    = threadIdx.x >> 6;        // wave = head
    const int lane = threadIdx.x & 63;
    const int iL   = lane & 15;
    const int quad = lane >> 4;
    const int i0   = blockIdx.x * 16;

    f32x4 acc[4];
    #pragma unroll
    for (int t = 0; t < 4; ++t) acc[t] = (f32x4){0.f, 0.f, 0.f, 0.f};

    const _Float16* arow = xh + (size_t)(i0 + iL) * FF + quad * 8;
    const _Float16* bbase = wt + (size_t)(h * 64 + iL) * FF + quad * 8;

    for (int kc = 0; kc < FF; kc += 32) {
        f16x8 a = *(const f16x8*)(arow + kc);
        #pragma unroll
        for (int t = 0; t < 4; ++t) {
            f16x8 b = *(const f16x8*)(bbase + (size_t)(16 * t) * FF + kc);
            acc[t] = mfma16(a, b, acc[t]);
        }
    }
    // C/D: row (=n) = quad*4+reg, col (=d-local) = lane&15
    #pragma unroll
    for (int t = 0; t < 4; ++t) {
        H4 o;
        #pragma unroll
        for (int r = 0; r < 4; ++r) o.h[r] = (_Float16)acc[t][r];
        *(ushort4*)(whT + (size_t)(h * 64 + 16 * t + iL) * NN + i0 + quad * 4) = o.u;
    }
}

// ---- s1L/s2L[h][n] = (Wh[h,n,:]·a)·log2e ----
__global__ __launch_bounds__(256) void k_s(const _Float16* __restrict__ whT,
                                           const float* __restrict__ a1,
                                           const float* __restrict__ a2,
                                           float* __restrict__ s1L,
                                           float* __restrict__ s2L) {
    int tid = blockIdx.x * 256 + threadIdx.x;  // H*N threads
    int h = tid >> 12, n = tid & 4095;
    float s1 = 0.f, s2 = 0.f;
    #pragma unroll 8
    for (int d = 0; d < DD; ++d) {
        float w = (float)whT[(size_t)(h * 64 + d) * NN + n];
        s1 += w * a1[h * 64 + d];
        s2 += w * a2[h * 64 + d];
    }
    s1L[tid] = s1 * LOG2E;
    s2L[tid] = s2 * LOG2E;
}

// ---- ci[h][n] = lrelu(s1L + max_j s2L)  (log2-domain row shift) ----
__global__ __launch_bounds__(256) void k_ci(const float* __restrict__ s1L,
                                            const float* __restrict__ s2L,
                                            float* __restrict__ ci) {
    __shared__ float red[4];
    int h = blockIdx.x, t = threadIdx.x;
    float mx = -1e30f;
    for (int n = t; n < NN; n += 256) mx = fmaxf(mx, s2L[h * NN + n]);
    #pragma unroll
    for (int off = 32; off > 0; off >>= 1) mx = fmaxf(mx, __shfl_down(mx, off));
    if ((t & 63) == 0) red[t >> 6] = mx;
    __syncthreads();
    float m4 = fmaxf(fmaxf(red[0], red[1]), fmaxf(red[2], red[3]));
    for (int n = t; n < NN; n += 256) {
        float v = s1L[h * NN + n] + m4;
        ci[h * NN + n] = fmaxf(v, ALPHA_LR * v);
    }
}

// ---- fused masked-attention + elu + metapath sum ----
// grid 256 blocks (16 rows each), 512 threads = 8 waves: wave = (head, j-half)
__global__ __launch_bounds__(512) void k_attn(const _Float16* __restrict__ whT,
                                              const float* __restrict__ s1L,
                                              const float* __restrict__ s2L,
                                              const float* __restrict__ ci,
                                              const uint32_t* __restrict__ bits,
                                              float* __restrict__ out) {
    __shared__ __align__(16) float xnum[HH][MM][4][16][16]; // [h][m][t][col][row]
    __shared__ __align__(16) float xden[HH][MM][16];

    const int tid  = threadIdx.x;
    const int wave = tid >> 6;
    const int h    = wave & 3;
    const int jh   = wave >> 2;
    const int lane = tid & 63;
    const int iL   = lane & 15;
    const int quad = lane >> 4;
    const int i0   = blockIdx.x * 16;
    const int i    = i0 + iL;

    const float s1i = s1L[h * NN + i];
    const float cii = ci[h * NN + i];

    f32x4 acc[MM][4];
    f32x4 accD[MM];
    #pragma unroll
    for (int m = 0; m < MM; ++m) {
        accD[m] = (f32x4){0.f, 0.f, 0.f, 0.f};
        #pragma unroll
        for (int t = 0; t < 4; ++t) acc[m][t] = (f32x4){0.f, 0.f, 0.f, 0.f};
    }

    f16x8 bones;
    #pragma unroll
    for (int e = 0; e < 8; ++e) bones[e] = (_Float16)1.0f;

    const uint32_t* bp0 = bits + (size_t)i * 128;            // m=0
    const uint32_t* bp1 = bits + (size_t)(NN + i) * 128;     // m=1
    const float* s2row = s2L + h * NN;
    const _Float16* brow = whT + (size_t)(h * 64 + iL) * NN;
    const int qshift = quad * 8;
    const int jbase = jh * 2048;

    for (int jc = jbase; jc < jbase + 2048; jc += 32) {
        const int w = jc >> 5;
        uint32_t rs0 = bp0[w] >> qshift;
        uint32_t rs1 = bp1[w] >> qshift;
        const float* s2p = s2row + jc + qshift;
        float4 sa = *(const float4*)s2p;
        float4 sb = *(const float4*)(s2p + 4);
        float s2v[8] = {sa.x, sa.y, sa.z, sa.w, sb.x, sb.y, sb.z, sb.w};

        float p[8];
        #pragma unroll
        for (int e = 0; e < 8; ++e) {
            float z = s1i + s2v[e];              // log2-domain
            float le = fmaxf(z, ALPHA_LR * z);   // leaky_relu (scale-invariant)
            p[e] = fast_exp2(le - cii);          // <= 1
        }

        f16x8 a0, a1v;
        #pragma unroll
        for (int e = 0; e < 8; ++e) {
            a0[e]  = (_Float16)((rs0 & (1u << e)) ? p[e] : 0.f);
            a1v[e] = (_Float16)((rs1 & (1u << e)) ? p[e] : 0.f);
        }

        #pragma unroll
        for (int t = 0; t < 4; ++t) {
            f16x8 b = *(const f16x8*)(brow + (size_t)(16 * t) * NN + jc + qshift);
            acc[0][t] = mfma16(a0, b, acc[0][t]);
            acc[1][t] = mfma16(a1v, b, acc[1][t]);
        }
        accD[0] = mfma16(a0, bones, accD[0]);    // row sums -> denominator
        accD[1] = mfma16(a1v, bones, accD[1]);
    }

    if (jh == 1) {
        #pragma unroll
        for (int m = 0; m < MM; ++m) {
            #pragma unroll
            for (int t = 0; t < 4; ++t)
                *(f32x4*)&xnum[h][m][t][iL][quad * 4] = acc[m][t];
            if (iL == 0)
                *(f32x4*)&xden[h][m][quad * 4] = accD[m];
        }
    }
    __syncthreads();
    if (jh == 0) {
        #pragma unroll
        for (int m = 0; m < MM; ++m) {
            #pragma unroll
            for (int t = 0; t < 4; ++t)
                acc[m][t] += *(const f32x4*)&xnum[h][m][t][iL][quad * 4];
            accD[m] += *(const f32x4*)&xden[h][m][quad * 4];
        }
        #pragma unroll
        for (int t = 0; t < 4; ++t) {
            #pragma unroll
            for (int r = 0; r < 4; ++r) {
                float v0 = acc[0][t][r] * fast_rcp(accD[0][r]);
                float v1 = acc[1][t][r] * fast_rcp(accD[1][r]);
                float e0 = v0 > 0.f ? v0 : (fast_exp2(v0 * LOG2E) - 1.f);
                float e1 = v1 > 0.f ? v1 : (fast_exp2(v1 * LOG2E) - 1.f);
                out[(size_t)(i0 + quad * 4 + r) * (HH * DD) + h * 64 + 16 * t + iL] = e0 + e1;
            }
        }
    }
}

extern "C" void kernel_launch(void* const* d_in, const int* in_sizes, int n_in,
                              void* d_out, int out_size, void* d_ws, size_t ws_size,
                              hipStream_t stream) {
    const float* x   = (const float*)d_in[0];
    const int*   adj = (const int*)d_in[1];
    const float* W   = (const float*)d_in[2];
    const float* a1  = (const float*)d_in[3];
    const float* a2  = (const float*)d_in[4];
    // d_in[5..7] (Ws, bs, q_sem) mathematically dead: softmax over size-1 axis == 1
    float* out = (float*)d_out;

    char* ws = (char*)d_ws;
    _Float16* xh   = (_Float16*)(ws);                 // 4 MB
    _Float16* wt   = (_Float16*)(ws + 4194304);       // 256 KB
    _Float16* whT  = (_Float16*)(ws + 4456448);       // 2 MB
    float*    s1L  = (float*)(ws + 6553600);          // 64 KB
    float*    s2L  = (float*)(ws + 6619136);          // 64 KB
    float*    ci   = (float*)(ws + 6684672);          // 64 KB
    uint32_t* bits = (uint32_t*)(ws + 6750208);       // 4 MB

    hipLaunchKernelGGL(k_conv_x, dim3(2048), dim3(256), 0, stream, x, xh);
    hipLaunchKernelGGL(k_conv_w, dim3(512), dim3(256), 0, stream, W, wt);
    hipLaunchKernelGGL(k_pack, dim3(131072), dim3(256), 0, stream, adj, bits);
    hipLaunchKernelGGL(k_wh, dim3(256), dim3(256), 0, stream, xh, wt, whT);
    hipLaunchKernelGGL(k_s, dim3(64), dim3(256), 0, stream, whT, a1, a2, s1L, s2L);
    hipLaunchKernelGGL(k_ci, dim3(4), dim3(256), 0, stream, s1L, s2L, ci);
    hipLaunchKernelGGL(k_attn, dim3(256), dim3(512), 0, stream, whT, s1L, s2L, ci, bits, out);
}

// Round 3
// 339.934 us; speedup vs baseline: 1.0586x; 1.0586x over previous
//
#include <hip/hip_runtime.h>
#include <hip/hip_fp16.h>
#include <stdint.h>

#define NN 4096      // nodes
#define FF 512       // in features
#define DD 64        // head dim
#define HH 4         // heads
#define MM 2         // metapaths
#define LOG2E 1.44269504088896340736f
#define ALPHA_LR 0.2f

typedef float f32x4 __attribute__((ext_vector_type(4)));
typedef _Float16 f16x8 __attribute__((ext_vector_type(8)));
typedef _Float16 f16x2 __attribute__((ext_vector_type(2)));

union H4 { ushort4 u; _Float16 h[4]; };
union V8 { f16x8 v; f16x2 p[4]; };

__device__ inline float fast_exp2(float x) { return __builtin_amdgcn_exp2f(x); }
__device__ inline float fast_rcp(float x) { return __builtin_amdgcn_rcpf(x); }
__device__ inline f32x4 mfma16(f16x8 a, f16x8 b, f32x4 c) {
    return __builtin_amdgcn_mfma_f32_16x16x32_f16(a, b, c, 0, 0, 0);
}
__device__ inline f16x2 pkrtz(float a, float b) {
    return __builtin_bit_cast(f16x2, __builtin_amdgcn_cvt_pkrtz(a, b));
}
// order-preserving float->uint encode for atomicMax
__device__ inline uint32_t enc_f32(float f) {
    uint32_t u = __float_as_uint(f);
    return (u & 0x80000000u) ? ~u : (u | 0x80000000u);
}
__device__ inline float dec_f32(uint32_t k) {
    uint32_t u = (k & 0x80000000u) ? (k ^ 0x80000000u) : ~k;
    return __uint_as_float(u);
}

// ---- x [N,F] fp32 -> f16 (+ init m4 atomic slots) ----
__global__ __launch_bounds__(256) void k_conv_x(const float* __restrict__ x,
                                                _Float16* __restrict__ xh,
                                                uint32_t* __restrict__ m4a) {
    int t = blockIdx.x * 256 + threadIdx.x;   // N*F/4 threads
    if (t < HH) m4a[t] = 0u;                  // encoded -inf floor (any finite neg encodes > 0)
    float4 v = ((const float4*)x)[t];
    H4 o;
    o.h[0] = (_Float16)v.x; o.h[1] = (_Float16)v.y;
    o.h[2] = (_Float16)v.z; o.h[3] = (_Float16)v.w;
    ((ushort4*)xh)[t] = o.u;
}

// ---- W [H][F][D] fp32 -> W_T f16 [H*D][F] ----
__global__ __launch_bounds__(256) void k_conv_w(const float* __restrict__ W,
                                                _Float16* __restrict__ wt) {
    int t = blockIdx.x * 256 + threadIdx.x;   // 256*512 threads
    int c = t >> 9, f = t & 511;
    int h = c >> 6, d = c & 63;
    wt[t] = (_Float16)W[(h * FF + f) * DD + d];
}

// ---- adj int32 {0,1} -> bitmask [m][i][128 words], grid-stride ----
__global__ __launch_bounds__(256) void k_pack(const int* __restrict__ adj,
                                              uint32_t* __restrict__ bits) {
    const long long total = (long long)MM * NN * NN;      // 33554432
    const long long stride = 2048LL * 256;
    long long tid = (long long)blockIdx.x * 256 + threadIdx.x;
    for (long long e = tid; e < total; e += stride) {
        unsigned long long m = __ballot(adj[e] != 0);
        if ((threadIdx.x & 63) == 0)
            ((unsigned long long*)bits)[e >> 6] = m;
    }
}

// ---- Wh = x @ W[h], stored transposed f16: whT[h*64+d][n]; 8 waves/block ----
__global__ __launch_bounds__(512) void k_wh(const _Float16* __restrict__ xh,
                                            const _Float16* __restrict__ wt,
                                            _Float16* __restrict__ whT) {
    const int wave = threadIdx.x >> 6;
    const int h    = wave & 3;
    const int th   = wave >> 2;               // t-half: t in {2*th, 2*th+1}
    const int lane = threadIdx.x & 63;
    const int iL   = lane & 15;
    const int quad = lane >> 4;
    const int i0   = blockIdx.x * 16;

    f32x4 acc[2];
    acc[0] = (f32x4){0.f, 0.f, 0.f, 0.f};
    acc[1] = (f32x4){0.f, 0.f, 0.f, 0.f};

    const _Float16* arow  = xh + (size_t)(i0 + iL) * FF + quad * 8;
    const _Float16* bbase = wt + (size_t)(h * 64 + th * 32 + iL) * FF + quad * 8;

    for (int kc = 0; kc < FF; kc += 32) {
        f16x8 a = *(const f16x8*)(arow + kc);
        #pragma unroll
        for (int u = 0; u < 2; ++u) {
            f16x8 b = *(const f16x8*)(bbase + (size_t)(16 * u) * FF + kc);
            acc[u] = mfma16(a, b, acc[u]);
        }
    }
    // C/D: row (=n) = quad*4+reg, col (=d-local) = lane&15
    #pragma unroll
    for (int u = 0; u < 2; ++u) {
        H4 o;
        #pragma unroll
        for (int r = 0; r < 4; ++r) o.h[r] = (_Float16)acc[u][r];
        *(ushort4*)(whT + (size_t)(h * 64 + th * 32 + 16 * u + iL) * NN + i0 + quad * 4) = o.u;
    }
}

// ---- s1L/s2L[h][n] = (Wh[h,n,:]·a)·log2e ; per-head max(s2L) via atomicMax ----
__global__ __launch_bounds__(64) void k_s(const _Float16* __restrict__ whT,
                                          const float* __restrict__ a1,
                                          const float* __restrict__ a2,
                                          float* __restrict__ s1L,
                                          float* __restrict__ s2L,
                                          uint32_t* __restrict__ m4a) {
    int b = blockIdx.x;                        // 256 blocks x 64 threads
    int h = b >> 6;
    int n = (b & 63) * 64 + threadIdx.x;
    float s1 = 0.f, s2 = 0.f;
    #pragma unroll 8
    for (int d = 0; d < DD; ++d) {
        float w = (float)whT[(size_t)(h * 64 + d) * NN + n];
        s1 += w * a1[h * 64 + d];
        s2 += w * a2[h * 64 + d];
    }
    float s2l = s2 * LOG2E;
    s1L[h * NN + n] = s1 * LOG2E;
    s2L[h * NN + n] = s2l;
    float mx = s2l;
    #pragma unroll
    for (int off = 32; off > 0; off >>= 1) mx = fmaxf(mx, __shfl_down(mx, off));
    if (threadIdx.x == 0) atomicMax(m4a + h, enc_f32(mx));
}

// ---- fused masked-attention + elu + metapath sum ----
// grid 1024 = (i-tile x head); 512 threads = 8 waves = 8 j-slices of 512
__global__ __launch_bounds__(512) void k_attn(const _Float16* __restrict__ whT,
                                              const float* __restrict__ s1L,
                                              const float* __restrict__ s2L,
                                              const uint32_t* __restrict__ m4a,
                                              const uint32_t* __restrict__ bits,
                                              float* __restrict__ out) {
    __shared__ __align__(16) float xr[4][MM][4][16][16]; // [slot][m][t][col][row]
    __shared__ __align__(16) float dr[4][MM][16];

    const int tid  = threadIdx.x;
    const int wave = tid >> 6;
    const int lane = tid & 63;
    const int iL   = lane & 15;
    const int quad = lane >> 4;
    const int h    = blockIdx.x & 3;
    const int i0   = (blockIdx.x >> 2) * 16;
    const int i    = i0 + iL;

    const float s1i = s1L[h * NN + i];
    const float m4  = dec_f32(m4a[h]);
    const float vv  = s1i + m4;
    const float cii = fmaxf(vv, ALPHA_LR * vv);           // lrelu row shift
    const float A   = s1i - cii;                          // arg = max(s2+A, a*s2+B)
    const float B   = ALPHA_LR * s1i - cii;

    f32x4 acc[MM][4];
    f32x4 accD[MM];
    #pragma unroll
    for (int m = 0; m < MM; ++m) {
        accD[m] = (f32x4){0.f, 0.f, 0.f, 0.f};
        #pragma unroll
        for (int t = 0; t < 4; ++t) acc[m][t] = (f32x4){0.f, 0.f, 0.f, 0.f};
    }

    f16x8 bones;
    #pragma unroll
    for (int e = 0; e < 8; ++e) bones[e] = (_Float16)1.0f;

    const uint32_t* bp0 = bits + (size_t)i * 128;            // m=0
    const uint32_t* bp1 = bits + (size_t)(NN + i) * 128;     // m=1
    const float* s2row = s2L + h * NN;
    const _Float16* brow = whT + (size_t)(h * 64 + iL) * NN;
    const int qshift = quad * 8;
    const int jbase = wave * 512;

    for (int jc = jbase; jc < jbase + 512; jc += 32) {
        const int w = jc >> 5;
        uint32_t rs0 = bp0[w] >> qshift;
        uint32_t rs1 = bp1[w] >> qshift;
        const float* s2p = s2row + jc + qshift;
        float4 sa = *(const float4*)s2p;
        float4 sb = *(const float4*)(s2p + 4);
        float s2v[8] = {sa.x, sa.y, sa.z, sa.w, sb.x, sb.y, sb.z, sb.w};

        float p[8];
        #pragma unroll
        for (int e = 0; e < 8; ++e) {
            float arg = fmaxf(s2v[e] + A, __builtin_fmaf(ALPHA_LR, s2v[e], B));
            p[e] = fast_exp2(arg);               // <= 1
        }

        V8 a0, a1v;
        #pragma unroll
        for (int e = 0; e < 4; ++e) {
            float q0 = (rs0 & (1u << (2 * e)))     ? p[2 * e]     : 0.f;
            float q1 = (rs0 & (1u << (2 * e + 1))) ? p[2 * e + 1] : 0.f;
            float r0 = (rs1 & (1u << (2 * e)))     ? p[2 * e]     : 0.f;
            float r1 = (rs1 & (1u << (2 * e + 1))) ? p[2 * e + 1] : 0.f;
            a0.p[e]  = pkrtz(q0, q1);
            a1v.p[e] = pkrtz(r0, r1);
        }

        #pragma unroll
        for (int t = 0; t < 4; ++t) {
            f16x8 b = *(const f16x8*)(brow + (size_t)(16 * t) * NN + jc + qshift);
            acc[0][t] = mfma16(a0.v, b, acc[0][t]);
            acc[1][t] = mfma16(a1v.v, b, acc[1][t]);
        }
        accD[0] = mfma16(a0.v, bones, accD[0]);    // row sums -> denominator
        accD[1] = mfma16(a1v.v, bones, accD[1]);
    }

    // ---- 3-stage LDS tree reduction over 8 wave-partials ----
    #define STORE_SLOT(s)                                                     \
        { _Pragma("unroll") for (int m = 0; m < MM; ++m) {                    \
              _Pragma("unroll") for (int t = 0; t < 4; ++t)                   \
                  *(f32x4*)&xr[s][m][t][iL][quad * 4] = acc[m][t];            \
              if (iL == 0) *(f32x4*)&dr[s][m][quad * 4] = accD[m]; } }
    #define ADD_SLOT(s)                                                       \
        { _Pragma("unroll") for (int m = 0; m < MM; ++m) {                    \
              _Pragma("unroll") for (int t = 0; t < 4; ++t)                   \
                  acc[m][t] += *(const f32x4*)&xr[s][m][t][iL][quad * 4];     \
              accD[m] += *(const f32x4*)&dr[s][m][quad * 4]; } }

    if (wave >= 4) STORE_SLOT(wave - 4);
    __syncthreads();
    if (wave < 4) ADD_SLOT(wave);
    __syncthreads();
    if (wave >= 2 && wave < 4) STORE_SLOT(wave - 2);
    __syncthreads();
    if (wave < 2) ADD_SLOT(wave);
    __syncthreads();
    if (wave == 1) STORE_SLOT(0);
    __syncthreads();
    if (wave == 0) {
        ADD_SLOT(0);
        #pragma unroll
        for (int t = 0; t < 4; ++t) {
            #pragma unroll
            for (int r = 0; r < 4; ++r) {
                float v0 = acc[0][t][r] * fast_rcp(accD[0][r]);
                float v1 = acc[1][t][r] * fast_rcp(accD[1][r]);
                float e0 = v0 > 0.f ? v0 : (fast_exp2(v0 * LOG2E) - 1.f);
                float e1 = v1 > 0.f ? v1 : (fast_exp2(v1 * LOG2E) - 1.f);
                out[(size_t)(i0 + quad * 4 + r) * (HH * DD) + h * 64 + 16 * t + iL] = e0 + e1;
            }
        }
    }
    #undef STORE_SLOT
    #undef ADD_SLOT
}

extern "C" void kernel_launch(void* const* d_in, const int* in_sizes, int n_in,
                              void* d_out, int out_size, void* d_ws, size_t ws_size,
                              hipStream_t stream) {
    const float* x   = (const float*)d_in[0];
    const int*   adj = (const int*)d_in[1];
    const float* W   = (const float*)d_in[2];
    const float* a1  = (const float*)d_in[3];
    const float* a2  = (const float*)d_in[4];
    // d_in[5..7] (Ws, bs, q_sem) mathematically dead: softmax over size-1 axis == 1
    float* out = (float*)d_out;

    char* ws = (char*)d_ws;
    _Float16* xh   = (_Float16*)(ws);                 // 4 MB
    _Float16* wt   = (_Float16*)(ws + 4194304);       // 256 KB
    _Float16* whT  = (_Float16*)(ws + 4456448);       // 2 MB
    float*    s1L  = (float*)(ws + 6553600);          // 64 KB
    float*    s2L  = (float*)(ws + 6619136);          // 64 KB
    uint32_t* m4a  = (uint32_t*)(ws + 6684672);       // 16 B (encoded per-head max)
    uint32_t* bits = (uint32_t*)(ws + 6750208);       // 4 MB

    hipLaunchKernelGGL(k_conv_x, dim3(2048), dim3(256), 0, stream, x, xh, m4a);
    hipLaunchKernelGGL(k_conv_w, dim3(512), dim3(256), 0, stream, W, wt);
    hipLaunchKernelGGL(k_pack, dim3(2048), dim3(256), 0, stream, adj, bits);
    hipLaunchKernelGGL(k_wh, dim3(256), dim3(512), 0, stream, xh, wt, whT);
    hipLaunchKernelGGL(k_s, dim3(256), dim3(64), 0, stream, whT, a1, a2, s1L, s2L, m4a);
    hipLaunchKernelGGL(k_attn, dim3(1024), dim3(512), 0, stream, whT, s1L, s2L, m4a, bits, out);
}

// Round 4
// 287.870 us; speedup vs baseline: 1.2501x; 1.1809x over previous
//
#include <hip/hip_runtime.h>
#include <hip/hip_fp16.h>
#include <stdint.h>

#define NN 4096      // nodes
#define FF 512       // in features
#define DD 64        // head dim
#define HH 4         // heads
#define MM 2         // metapaths
#define LOG2E 1.44269504088896340736f
#define ALPHA_LR 0.2f

typedef float f32x4 __attribute__((ext_vector_type(4)));
typedef _Float16 f16x8 __attribute__((ext_vector_type(8)));
typedef _Float16 f16x2 __attribute__((ext_vector_type(2)));

union H4 { ushort4 u; _Float16 h[4]; };
union V8 { f16x8 v; f16x2 p[4]; };

__device__ inline float fast_exp2(float x) { return __builtin_amdgcn_exp2f(x); }
__device__ inline float fast_rcp(float x) { return __builtin_amdgcn_rcpf(x); }
__device__ inline f32x4 mfma16(f16x8 a, f16x8 b, f32x4 c) {
    return __builtin_amdgcn_mfma_f32_16x16x32_f16(a, b, c, 0, 0, 0);
}
__device__ inline f16x2 pkrtz(float a, float b) {
    return __builtin_bit_cast(f16x2, __builtin_amdgcn_cvt_pkrtz(a, b));
}
// order-preserving float->uint encode for atomicMax
__device__ inline uint32_t enc_f32(float f) {
    uint32_t u = __float_as_uint(f);
    return (u & 0x80000000u) ? ~u : (u | 0x80000000u);
}
__device__ inline float dec_f32(uint32_t k) {
    uint32_t u = (k & 0x80000000u) ? (k ^ 0x80000000u) : ~k;
    return __uint_as_float(u);
}

// ---- x [N,F] fp32 -> f16 (+ init m4 atomic slots) ----
__global__ __launch_bounds__(256) void k_conv_x(const float* __restrict__ x,
                                                _Float16* __restrict__ xh,
                                                uint32_t* __restrict__ m4a) {
    int t = blockIdx.x * 256 + threadIdx.x;   // N*F/4 threads
    if (t < HH) m4a[t] = 0u;                  // encoded floor
    float4 v = ((const float4*)x)[t];
    H4 o;
    o.h[0] = (_Float16)v.x; o.h[1] = (_Float16)v.y;
    o.h[2] = (_Float16)v.z; o.h[3] = (_Float16)v.w;
    ((ushort4*)xh)[t] = o.u;
}

// ---- W [H][F][D] fp32 -> W_T f16 [H*D][F] ----
__global__ __launch_bounds__(256) void k_conv_w(const float* __restrict__ W,
                                                _Float16* __restrict__ wt) {
    int t = blockIdx.x * 256 + threadIdx.x;   // 256*512 threads
    int c = t >> 9, f = t & 511;
    int h = c >> 6, d = c & 63;
    wt[t] = (_Float16)W[(h * FF + f) * DD + d];
}

// ---- adj int32 {0,1} -> TRANSPOSED bitmask bitsT[m][jw][i] (ull units) ----
__global__ __launch_bounds__(256) void k_pack(const int* __restrict__ adj,
                                              unsigned long long* __restrict__ bitsT) {
    const long long total = (long long)MM * NN * NN;      // 33554432
    const long long stride = 2048LL * 256;
    long long tid = (long long)blockIdx.x * 256 + threadIdx.x;
    for (long long e = tid; e < total; e += stride) {
        unsigned long long msk = __ballot(adj[e] != 0);
        if ((threadIdx.x & 63) == 0) {
            long long q = e >> 6;                  // global 64-bit word index
            int m  = (int)(q >> 18);               // 4096*64 words per metapath
            int rem = (int)(q & 262143);
            int i  = rem >> 6;
            int jw = rem & 63;
            bitsT[((size_t)m * 64 + jw) * NN + i] = msk;
        }
    }
}

// ---- Wh = x @ W[h], stored transposed f16: whT[h*64+d][n]; 8 waves/block ----
__global__ __launch_bounds__(512) void k_wh(const _Float16* __restrict__ xh,
                                            const _Float16* __restrict__ wt,
                                            _Float16* __restrict__ whT) {
    const int wave = threadIdx.x >> 6;
    const int h    = wave & 3;
    const int th   = wave >> 2;
    const int lane = threadIdx.x & 63;
    const int iL   = lane & 15;
    const int quad = lane >> 4;
    const int i0   = blockIdx.x * 16;

    f32x4 acc[2];
    acc[0] = (f32x4){0.f, 0.f, 0.f, 0.f};
    acc[1] = (f32x4){0.f, 0.f, 0.f, 0.f};

    const _Float16* arow  = xh + (size_t)(i0 + iL) * FF + quad * 8;
    const _Float16* bbase = wt + (size_t)(h * 64 + th * 32 + iL) * FF + quad * 8;

    for (int kc = 0; kc < FF; kc += 32) {
        f16x8 a = *(const f16x8*)(arow + kc);
        #pragma unroll
        for (int u = 0; u < 2; ++u) {
            f16x8 b = *(const f16x8*)(bbase + (size_t)(16 * u) * FF + kc);
            acc[u] = mfma16(a, b, acc[u]);
        }
    }
    #pragma unroll
    for (int u = 0; u < 2; ++u) {
        H4 o;
        #pragma unroll
        for (int r = 0; r < 4; ++r) o.h[r] = (_Float16)acc[u][r];
        *(ushort4*)(whT + (size_t)(h * 64 + th * 32 + 16 * u + iL) * NN + i0 + quad * 4) = o.u;
    }
}

// ---- s1L/s2L[h][n] = (Wh[h,n,:]·a)·log2e ; per-head max(s2L) via atomicMax ----
__global__ __launch_bounds__(64) void k_s(const _Float16* __restrict__ whT,
                                          const float* __restrict__ a1,
                                          const float* __restrict__ a2,
                                          float* __restrict__ s1L,
                                          float* __restrict__ s2L,
                                          uint32_t* __restrict__ m4a) {
    int b = blockIdx.x;                        // 256 blocks x 64 threads
    int h = b >> 6;
    int n = (b & 63) * 64 + threadIdx.x;
    float s1 = 0.f, s2 = 0.f;
    #pragma unroll 8
    for (int d = 0; d < DD; ++d) {
        float w = (float)whT[(size_t)(h * 64 + d) * NN + n];
        s1 += w * a1[h * 64 + d];
        s2 += w * a2[h * 64 + d];
    }
    float s2l = s2 * LOG2E;
    s1L[h * NN + n] = s1 * LOG2E;
    s2L[h * NN + n] = s2l;
    float mx = s2l;
    #pragma unroll
    for (int off = 32; off > 0; off >>= 1) mx = fmaxf(mx, __shfl_down(mx, off));
    if (threadIdx.x == 0) atomicMax(m4a + h, enc_f32(mx));
}

// ---- fused masked-attention + elu + metapath sum ----
// grid 256 = (i-group of 64 rows) x head; 512 thr = 8 waves = 8 j-slices of 512.
// Each wave computes 4 i-subtiles (b-frag loads amortized 4x).
__global__ __launch_bounds__(512, 2) void k_attn(const _Float16* __restrict__ whT,
                                                 const float* __restrict__ s1L,
                                                 const float* __restrict__ s2L,
                                                 const uint32_t* __restrict__ m4a,
                                                 const unsigned long long* __restrict__ bitsT,
                                                 float* __restrict__ out) {
    __shared__ __align__(16) float xr[4][MM][4][16][16]; // [slot][m][t][col][row]
    __shared__ __align__(16) float dr[4][MM][16];

    const int tid  = threadIdx.x;
    const int wave = tid >> 6;
    const int lane = tid & 63;
    const int iL   = lane & 15;
    const int quad = lane >> 4;
    const int h    = blockIdx.x & 3;
    const int i0   = (blockIdx.x >> 2) * 64;      // 64 i-rows per block

    const float m4 = dec_f32(m4a[h]);
    float A[4], B[4];
    #pragma unroll
    for (int s = 0; s < 4; ++s) {
        float s1i = s1L[h * NN + i0 + 16 * s + iL];
        float vv  = s1i + m4;
        float cii = fmaxf(vv, ALPHA_LR * vv);     // lrelu row shift (log2 domain)
        A[s] = s1i - cii;
        B[s] = ALPHA_LR * s1i - cii;
    }

    f32x4 acc[4][MM][4];
    f32x4 accD[4][MM];
    #pragma unroll
    for (int s = 0; s < 4; ++s)
        #pragma unroll
        for (int m = 0; m < MM; ++m) {
            accD[s][m] = (f32x4){0.f, 0.f, 0.f, 0.f};
            #pragma unroll
            for (int t = 0; t < 4; ++t) acc[s][m][t] = (f32x4){0.f, 0.f, 0.f, 0.f};
        }

    f16x8 bones;
    #pragma unroll
    for (int e = 0; e < 8; ++e) bones[e] = (_Float16)1.0f;

    const float* s2row = s2L + h * NN;
    const _Float16* brow = whT + (size_t)(h * 64 + iL) * NN;   // + 16t*NN + j
    const int qshift = quad * 8;
    const int jbase = wave * 512;

    // bits base pointers per (m, subtile): + jw*NN per iteration
    const unsigned long long* pB[MM][4];
    #pragma unroll
    for (int m = 0; m < MM; ++m)
        #pragma unroll
        for (int s = 0; s < 4; ++s)
            pB[m][s] = bitsT + (size_t)m * 64 * NN + i0 + 16 * s + iL;

    for (int it = 0; it < 8; ++it) {
        const int jc = jbase + it * 64;
        const int jw = jc >> 6;
        unsigned long long bm[MM][4];
        #pragma unroll
        for (int m = 0; m < MM; ++m)
            #pragma unroll
            for (int s = 0; s < 4; ++s)
                bm[m][s] = pB[m][s][(size_t)jw * NN];

        #pragma unroll
        for (int half = 0; half < 2; ++half) {
            const int jb = jc + 32 * half;
            // shared b-fragments (amortized over 4 subtiles)
            f16x8 bfr[4];
            #pragma unroll
            for (int t = 0; t < 4; ++t)
                bfr[t] = *(const f16x8*)(brow + (size_t)(16 * t) * NN + jb + qshift);

            const float* s2p = s2row + jb + qshift;
            float4 sa = *(const float4*)s2p;
            float4 sb = *(const float4*)(s2p + 4);
            float s2v[8] = {sa.x, sa.y, sa.z, sa.w, sb.x, sb.y, sb.z, sb.w};
            const int shft = 32 * half + qshift;

            #pragma unroll
            for (int s = 0; s < 4; ++s) {
                float p[8];
                #pragma unroll
                for (int e = 0; e < 8; ++e) {
                    float arg = fmaxf(s2v[e] + A[s], __builtin_fmaf(ALPHA_LR, s2v[e], B[s]));
                    p[e] = fast_exp2(arg);
                }
                uint32_t rs0 = (uint32_t)(bm[0][s] >> shft);
                uint32_t rs1 = (uint32_t)(bm[1][s] >> shft);
                V8 a0, a1v;
                #pragma unroll
                for (int e = 0; e < 4; ++e) {
                    float q0 = (rs0 & (1u << (2 * e)))     ? p[2 * e]     : 0.f;
                    float q1 = (rs0 & (1u << (2 * e + 1))) ? p[2 * e + 1] : 0.f;
                    float r0 = (rs1 & (1u << (2 * e)))     ? p[2 * e]     : 0.f;
                    float r1 = (rs1 & (1u << (2 * e + 1))) ? p[2 * e + 1] : 0.f;
                    a0.p[e]  = pkrtz(q0, q1);
                    a1v.p[e] = pkrtz(r0, r1);
                }
                #pragma unroll
                for (int t = 0; t < 4; ++t) {
                    acc[s][0][t] = mfma16(a0.v, bfr[t], acc[s][0][t]);
                    acc[s][1][t] = mfma16(a1v.v, bfr[t], acc[s][1][t]);
                }
                accD[s][0] = mfma16(a0.v, bones, accD[s][0]);
                accD[s][1] = mfma16(a1v.v, bones, accD[s][1]);
            }
        }
    }

    // ---- per-subtile 3-stage LDS tree reduction over 8 wave j-slices ----
    #define STORE_SLOT(sl, s)                                                 \
        { _Pragma("unroll") for (int m = 0; m < MM; ++m) {                    \
              _Pragma("unroll") for (int t = 0; t < 4; ++t)                   \
                  *(f32x4*)&xr[sl][m][t][iL][quad * 4] = acc[s][m][t];        \
              if (iL == 0) *(f32x4*)&dr[sl][m][quad * 4] = accD[s][m]; } }
    #define ADD_SLOT(sl, s)                                                   \
        { _Pragma("unroll") for (int m = 0; m < MM; ++m) {                    \
              _Pragma("unroll") for (int t = 0; t < 4; ++t)                   \
                  acc[s][m][t] += *(const f32x4*)&xr[sl][m][t][iL][quad * 4]; \
              accD[s][m] += *(const f32x4*)&dr[sl][m][quad * 4]; } }

    for (int s = 0; s < 4; ++s) {
        __syncthreads();
        if (wave >= 4) STORE_SLOT(wave - 4, s);
        __syncthreads();
        if (wave < 4) ADD_SLOT(wave, s);
        __syncthreads();
        if (wave >= 2 && wave < 4) STORE_SLOT(wave - 2, s);
        __syncthreads();
        if (wave < 2) ADD_SLOT(wave, s);
        __syncthreads();
        if (wave == 1) STORE_SLOT(0, s);
        __syncthreads();
        if (wave == 0) {
            ADD_SLOT(0, s);
            const int i0s = i0 + 16 * s;
            #pragma unroll
            for (int t = 0; t < 4; ++t) {
                #pragma unroll
                for (int r = 0; r < 4; ++r) {
                    float v0 = acc[s][0][t][r] * fast_rcp(accD[s][0][r]);
                    float v1 = acc[s][1][t][r] * fast_rcp(accD[s][1][r]);
                    float e0 = v0 > 0.f ? v0 : (fast_exp2(v0 * LOG2E) - 1.f);
                    float e1 = v1 > 0.f ? v1 : (fast_exp2(v1 * LOG2E) - 1.f);
                    out[(size_t)(i0s + quad * 4 + r) * (HH * DD) + h * 64 + 16 * t + iL] = e0 + e1;
                }
            }
        }
    }
    #undef STORE_SLOT
    #undef ADD_SLOT
}

extern "C" void kernel_launch(void* const* d_in, const int* in_sizes, int n_in,
                              void* d_out, int out_size, void* d_ws, size_t ws_size,
                              hipStream_t stream) {
    const float* x   = (const float*)d_in[0];
    const int*   adj = (const int*)d_in[1];
    const float* W   = (const float*)d_in[2];
    const float* a1  = (const float*)d_in[3];
    const float* a2  = (const float*)d_in[4];
    // d_in[5..7] (Ws, bs, q_sem) mathematically dead: softmax over size-1 axis == 1
    float* out = (float*)d_out;

    char* ws = (char*)d_ws;
    _Float16* xh   = (_Float16*)(ws);                 // 4 MB
    _Float16* wt   = (_Float16*)(ws + 4194304);       // 256 KB
    _Float16* whT  = (_Float16*)(ws + 4456448);       // 2 MB
    float*    s1L  = (float*)(ws + 6553600);          // 64 KB
    float*    s2L  = (float*)(ws + 6619136);          // 64 KB
    uint32_t* m4a  = (uint32_t*)(ws + 6684672);       // 16 B
    unsigned long long* bitsT = (unsigned long long*)(ws + 6750208); // 4 MB

    hipLaunchKernelGGL(k_conv_x, dim3(2048), dim3(256), 0, stream, x, xh, m4a);
    hipLaunchKernelGGL(k_conv_w, dim3(512), dim3(256), 0, stream, W, wt);
    hipLaunchKernelGGL(k_pack, dim3(2048), dim3(256), 0, stream, adj, bitsT);
    hipLaunchKernelGGL(k_wh, dim3(256), dim3(512), 0, stream, xh, wt, whT);
    hipLaunchKernelGGL(k_s, dim3(256), dim3(64), 0, stream, whT, a1, a2, s1L, s2L, m4a);
    hipLaunchKernelGGL(k_attn, dim3(256), dim3(512), 0, stream, whT, s1L, s2L, m4a, bitsT, out);
}

// Round 6
// 276.111 us; speedup vs baseline: 1.3033x; 1.0426x over previous
//
#include <hip/hip_runtime.h>
#include <hip/hip_fp16.h>
#include <stdint.h>

#define NN 4096      // nodes
#define FF 512       // in features
#define DD 64        // head dim
#define HH 4         // heads
#define MM 2         // metapaths
#define LOG2E 1.44269504088896340736f
#define ALPHA_LR 0.2f

typedef float f32x4 __attribute__((ext_vector_type(4)));
typedef _Float16 f16x8 __attribute__((ext_vector_type(8)));
typedef _Float16 f16x2 __attribute__((ext_vector_type(2)));

extern "C" __device__ _Float16 __ocml_exp2_f16(_Float16);

union H4 { ushort4 u; _Float16 h[4]; };
union W8 { f16x8 v; uint32_t w[4]; f16x2 p[4]; };

__device__ inline float fast_exp2(float x) { return __builtin_amdgcn_exp2f(x); }
__device__ inline float fast_rcp(float x) { return __builtin_amdgcn_rcpf(x); }
__device__ inline f32x4 mfma16(f16x8 a, f16x8 b, f32x4 c) {
    return __builtin_amdgcn_mfma_f32_16x16x32_f16(a, b, c, 0, 0, 0);
}
// order-preserving float->uint encode for atomicMax
__device__ inline uint32_t enc_f32(float f) {
    uint32_t u = __float_as_uint(f);
    return (u & 0x80000000u) ? ~u : (u | 0x80000000u);
}
__device__ inline float dec_f32(uint32_t k) {
    uint32_t u = (k & 0x80000000u) ? (k ^ 0x80000000u) : ~k;
    return __uint_as_float(u);
}
// per-f16-pair AND-mask from two adjacency bits
__device__ inline uint32_t mpair(uint32_t rs, int k) {
    return (((rs >> (2 * k)) & 1u) ? 0x0000FFFFu : 0u) |
           (((rs >> (2 * k + 1)) & 1u) ? 0xFFFF0000u : 0u);
}

// ---- fused prep: [0,2048) pack adj->bitsT ; [2048,4096) x->f16 ; [4096,4608) W->wtT ----
__global__ __launch_bounds__(256) void k_prep(const float* __restrict__ x,
                                              const int* __restrict__ adj,
                                              const float* __restrict__ W,
                                              _Float16* __restrict__ xh,
                                              _Float16* __restrict__ wt,
                                              unsigned long long* __restrict__ bitsT,
                                              uint32_t* __restrict__ m4a) {
    const int bid = blockIdx.x;
    if (bid < 2048) {
        // adj int32 {0,1} -> TRANSPOSED bitmask bitsT[m][jw][i] (ull units)
        const long long total = (long long)MM * NN * NN;      // 33554432
        const long long stride = 2048LL * 256;
        long long tid = (long long)bid * 256 + threadIdx.x;
        for (long long e = tid; e < total; e += stride) {
            unsigned long long msk = __ballot(adj[e] != 0);
            if ((threadIdx.x & 63) == 0) {
                long long q = e >> 6;
                int m  = (int)(q >> 18);
                int rem = (int)(q & 262143);
                int i  = rem >> 6;
                int jw = rem & 63;
                bitsT[((size_t)m * 64 + jw) * NN + i] = msk;
            }
        }
    } else if (bid < 4096) {
        int t = (bid - 2048) * 256 + threadIdx.x;  // N*F/4
        if (t < HH) m4a[t] = 0u;                   // encoded floor
        float4 v = ((const float4*)x)[t];
        H4 o;
        o.h[0] = (_Float16)v.x; o.h[1] = (_Float16)v.y;
        o.h[2] = (_Float16)v.z; o.h[3] = (_Float16)v.w;
        ((ushort4*)xh)[t] = o.u;
    } else {
        int t = (bid - 4096) * 256 + threadIdx.x;  // H*F*D
        int c = t >> 9, f = t & 511;
        int h = c >> 6, d = c & 63;
        wt[t] = (_Float16)W[(h * FF + f) * DD + d];
    }
}

// ---- Wh = x @ W[h] -> whT[h*64+d][n] f16 ; fused s1L/s2h/m4a from accumulators ----
__global__ __launch_bounds__(512) void k_wh(const _Float16* __restrict__ xh,
                                            const _Float16* __restrict__ wt,
                                            const float* __restrict__ a1,
                                            const float* __restrict__ a2,
                                            _Float16* __restrict__ whT,
                                            float* __restrict__ s1L,
                                            _Float16* __restrict__ s2h,
                                            uint32_t* __restrict__ m4a) {
    __shared__ float sred[8][2][16];
    const int wave = threadIdx.x >> 6;
    const int h    = wave & 3;
    const int th   = wave >> 2;
    const int lane = threadIdx.x & 63;
    const int iL   = lane & 15;
    const int quad = lane >> 4;
    const int i0   = blockIdx.x * 16;

    f32x4 acc[2];
    acc[0] = (f32x4){0.f, 0.f, 0.f, 0.f};
    acc[1] = (f32x4){0.f, 0.f, 0.f, 0.f};

    const _Float16* arow  = xh + (size_t)(i0 + iL) * FF + quad * 8;
    const _Float16* bbase = wt + (size_t)(h * 64 + th * 32 + iL) * FF + quad * 8;

    for (int kc = 0; kc < FF; kc += 32) {
        f16x8 a = *(const f16x8*)(arow + kc);
        #pragma unroll
        for (int u = 0; u < 2; ++u) {
            f16x8 b = *(const f16x8*)(bbase + (size_t)(16 * u) * FF + kc);
            acc[u] = mfma16(a, b, acc[u]);
        }
    }
    #pragma unroll
    for (int u = 0; u < 2; ++u) {
        H4 o;
        #pragma unroll
        for (int r = 0; r < 4; ++r) o.h[r] = (_Float16)acc[u][r];
        *(ushort4*)(whT + (size_t)(h * 64 + th * 32 + 16 * u + iL) * NN + i0 + quad * 4) = o.u;
    }

    // ---- fused s1/s2: dot over this wave's 32 d's, butterfly over iL, LDS over th ----
    const float a1v0 = a1[h * 64 + th * 32 + iL];
    const float a1v1 = a1[h * 64 + th * 32 + 16 + iL];
    const float a2v0 = a2[h * 64 + th * 32 + iL];
    const float a2v1 = a2[h * 64 + th * 32 + 16 + iL];
    #pragma unroll
    for (int r = 0; r < 4; ++r) {
        float p1 = acc[0][r] * a1v0 + acc[1][r] * a1v1;
        float p2 = acc[0][r] * a2v0 + acc[1][r] * a2v1;
        #pragma unroll
        for (int off = 1; off < 16; off <<= 1) {
            p1 += __shfl_xor(p1, off);
            p2 += __shfl_xor(p2, off);
        }
        if (iL == 0) {
            sred[wave][0][quad * 4 + r] = p1;
            sred[wave][1][quad * 4 + r] = p2;
        }
    }
    __syncthreads();
    if (threadIdx.x < 64) {
        int h2  = threadIdx.x >> 4;
        int idx = threadIdx.x & 15;
        float s1 = sred[h2][0][idx] + sred[h2 + 4][0][idx];
        float s2 = sred[h2][1][idx] + sred[h2 + 4][1][idx];
        float s2l = s2 * LOG2E;
        s1L[h2 * NN + i0 + idx] = s1 * LOG2E;
        s2h[h2 * NN + i0 + idx] = (_Float16)s2l;
        float mx = s2l;
        #pragma unroll
        for (int off = 1; off < 16; off <<= 1) mx = fmaxf(mx, __shfl_xor(mx, off));
        if (idx == 0) atomicMax(m4a + h2, enc_f32(mx));
    }
}

// ---- fused masked-attention + elu + metapath sum ----
// grid 256 = (i-group of 64 rows) x head; 512 thr = 8 waves = 8 j-slices of 512.
// Each wave computes 4 i-subtiles; inner math in packed f16 (pk_add/pk_fma) +
// scalar v_max_f16 / v_exp_f16 (no packed exp exists on CDNA).
__global__ __launch_bounds__(512, 2) void k_attn(const _Float16* __restrict__ whT,
                                                 const float* __restrict__ s1L,
                                                 const _Float16* __restrict__ s2h,
                                                 const uint32_t* __restrict__ m4a,
                                                 const unsigned long long* __restrict__ bitsT,
                                                 float* __restrict__ out) {
    __shared__ __align__(16) float xr[4][MM][4][16][16]; // [slot][m][t][col][row]
    __shared__ __align__(16) float dr[4][MM][16];

    const int tid  = threadIdx.x;
    const int wave = tid >> 6;
    const int lane = tid & 63;
    const int iL   = lane & 15;
    const int quad = lane >> 4;
    const int h    = blockIdx.x & 3;
    const int i0   = (blockIdx.x >> 2) * 64;      // 64 i-rows per block

    const float m4 = dec_f32(m4a[h]);
    f16x2 A2[4], B2[4];
    #pragma unroll
    for (int s = 0; s < 4; ++s) {
        float s1i = s1L[h * NN + i0 + 16 * s + iL];
        float vv  = s1i + m4;
        float cii = fmaxf(vv, ALPHA_LR * vv);     // lrelu row shift (log2 domain)
        _Float16 a = (_Float16)(s1i - cii);
        _Float16 b = (_Float16)(ALPHA_LR * s1i - cii);
        A2[s] = (f16x2){a, a};
        B2[s] = (f16x2){b, b};
    }
    const f16x2 al2 = (f16x2){(_Float16)ALPHA_LR, (_Float16)ALPHA_LR};

    f32x4 acc[4][MM][4];
    f32x4 accD[4][MM];
    #pragma unroll
    for (int s = 0; s < 4; ++s)
        #pragma unroll
        for (int m = 0; m < MM; ++m) {
            accD[s][m] = (f32x4){0.f, 0.f, 0.f, 0.f};
            #pragma unroll
            for (int t = 0; t < 4; ++t) acc[s][m][t] = (f32x4){0.f, 0.f, 0.f, 0.f};
        }

    f16x8 bones;
    #pragma unroll
    for (int e = 0; e < 8; ++e) bones[e] = (_Float16)1.0f;

    const _Float16* s2row = s2h + h * NN;
    const _Float16* brow = whT + (size_t)(h * 64 + iL) * NN;   // + 16t*NN + j
    const int qshift = quad * 8;
    const int jbase = wave * 512;

    const unsigned long long* pB[MM][4];
    #pragma unroll
    for (int m = 0; m < MM; ++m)
        #pragma unroll
        for (int s = 0; s < 4; ++s)
            pB[m][s] = bitsT + (size_t)m * 64 * NN + i0 + 16 * s + iL;

    for (int it = 0; it < 8; ++it) {
        const int jc = jbase + it * 64;
        const int jw = jc >> 6;
        unsigned long long bm[MM][4];
        #pragma unroll
        for (int m = 0; m < MM; ++m)
            #pragma unroll
            for (int s = 0; s < 4; ++s)
                bm[m][s] = pB[m][s][(size_t)jw * NN];

        #pragma unroll
        for (int half = 0; half < 2; ++half) {
            const int jb = jc + 32 * half;
            // shared b-fragments (amortized over 4 subtiles)
            f16x8 bfr[4];
            #pragma unroll
            for (int t = 0; t < 4; ++t)
                bfr[t] = *(const f16x8*)(brow + (size_t)(16 * t) * NN + jb + qshift);

            const W8 s2v = *(const W8*)(s2row + jb + qshift);  // 8 f16 (4 pairs)
            const int shft = 32 * half + qshift;

            #pragma unroll
            for (int s = 0; s < 4; ++s) {
                uint32_t rs0 = (uint32_t)(bm[0][s] >> shft);
                uint32_t rs1 = (uint32_t)(bm[1][s] >> shft);
                W8 a0, a1v;
                #pragma unroll
                for (int k = 0; k < 4; ++k) {
                    f16x2 z = s2v.p[k] + A2[s];               // v_pk_add_f16
                    f16x2 l = al2 * s2v.p[k] + B2[s];         // v_pk_fma_f16
                    _Float16 m0 = z[0] > l[0] ? z[0] : l[0];
                    _Float16 m1 = z[1] > l[1] ? z[1] : l[1];
                    f16x2 p = (f16x2){__ocml_exp2_f16(m0), __ocml_exp2_f16(m1)};
                    uint32_t pw = __builtin_bit_cast(uint32_t, p);
                    a0.w[k]  = pw & mpair(rs0, k);
                    a1v.w[k] = pw & mpair(rs1, k);
                }
                #pragma unroll
                for (int t = 0; t < 4; ++t) {
                    acc[s][0][t] = mfma16(a0.v, bfr[t], acc[s][0][t]);
                    acc[s][1][t] = mfma16(a1v.v, bfr[t], acc[s][1][t]);
                }
                accD[s][0] = mfma16(a0.v, bones, accD[s][0]);
                accD[s][1] = mfma16(a1v.v, bones, accD[s][1]);
            }
        }
    }

    // ---- per-subtile 3-stage LDS tree reduction over 8 wave j-slices ----
    #define STORE_SLOT(sl, s)                                                 \
        { _Pragma("unroll") for (int m = 0; m < MM; ++m) {                    \
              _Pragma("unroll") for (int t = 0; t < 4; ++t)                   \
                  *(f32x4*)&xr[sl][m][t][iL][quad * 4] = acc[s][m][t];        \
              if (iL == 0) *(f32x4*)&dr[sl][m][quad * 4] = accD[s][m]; } }
    #define ADD_SLOT(sl, s)                                                   \
        { _Pragma("unroll") for (int m = 0; m < MM; ++m) {                    \
              _Pragma("unroll") for (int t = 0; t < 4; ++t)                   \
                  acc[s][m][t] += *(const f32x4*)&xr[sl][m][t][iL][quad * 4]; \
              accD[s][m] += *(const f32x4*)&dr[sl][m][quad * 4]; } }

    for (int s = 0; s < 4; ++s) {
        __syncthreads();
        if (wave >= 4) STORE_SLOT(wave - 4, s);
        __syncthreads();
        if (wave < 4) ADD_SLOT(wave, s);
        __syncthreads();
        if (wave >= 2 && wave < 4) STORE_SLOT(wave - 2, s);
        __syncthreads();
        if (wave < 2) ADD_SLOT(wave, s);
        __syncthreads();
        if (wave == 1) STORE_SLOT(0, s);
        __syncthreads();
        if (wave == 0) {
            ADD_SLOT(0, s);
            const int i0s = i0 + 16 * s;
            #pragma unroll
            for (int t = 0; t < 4; ++t) {
                #pragma unroll
                for (int r = 0; r < 4; ++r) {
                    float v0 = acc[s][0][t][r] * fast_rcp(accD[s][0][r]);
                    float v1 = acc[s][1][t][r] * fast_rcp(accD[s][1][r]);
                    float e0 = v0 > 0.f ? v0 : (fast_exp2(v0 * LOG2E) - 1.f);
                    float e1 = v1 > 0.f ? v1 : (fast_exp2(v1 * LOG2E) - 1.f);
                    out[(size_t)(i0s + quad * 4 + r) * (HH * DD) + h * 64 + 16 * t + iL] = e0 + e1;
                }
            }
        }
    }
    #undef STORE_SLOT
    #undef ADD_SLOT
}

extern "C" void kernel_launch(void* const* d_in, const int* in_sizes, int n_in,
                              void* d_out, int out_size, void* d_ws, size_t ws_size,
                              hipStream_t stream) {
    const float* x   = (const float*)d_in[0];
    const int*   adj = (const int*)d_in[1];
    const float* W   = (const float*)d_in[2];
    const float* a1  = (const float*)d_in[3];
    const float* a2  = (const float*)d_in[4];
    // d_in[5..7] (Ws, bs, q_sem) mathematically dead: softmax over size-1 axis == 1
    float* out = (float*)d_out;

    char* ws = (char*)d_ws;
    _Float16* xh   = (_Float16*)(ws);                 // 4 MB
    _Float16* wt   = (_Float16*)(ws + 4194304);       // 256 KB
    _Float16* whT  = (_Float16*)(ws + 4456448);       // 2 MB
    float*    s1L  = (float*)(ws + 6553600);          // 64 KB
    _Float16* s2h  = (_Float16*)(ws + 6619136);       // 32 KB
    uint32_t* m4a  = (uint32_t*)(ws + 6684672);       // 16 B
    unsigned long long* bitsT = (unsigned long long*)(ws + 6750208); // 4 MB

    hipLaunchKernelGGL(k_prep, dim3(4608), dim3(256), 0, stream,
                       x, adj, W, xh, wt, bitsT, m4a);
    hipLaunchKernelGGL(k_wh, dim3(256), dim3(512), 0, stream,
                       xh, wt, a1, a2, whT, s1L, s2h, m4a);
    hipLaunchKernelGGL(k_attn, dim3(256), dim3(512), 0, stream,
                       whT, s1L, s2h, m4a, bitsT, out);
}

// Round 7
// 268.797 us; speedup vs baseline: 1.3388x; 1.0272x over previous
//
#include <hip/hip_runtime.h>
#include <hip/hip_fp16.h>
#include <stdint.h>

#define NN 4096      // nodes
#define FF 512       // in features
#define DD 64        // head dim
#define HH 4         // heads
#define MM 2         // metapaths
#define LOG2E 1.44269504088896340736f
#define ALPHA_LR 0.2f

typedef float f32x4 __attribute__((ext_vector_type(4)));
typedef _Float16 f16x8 __attribute__((ext_vector_type(8)));
typedef _Float16 f16x2 __attribute__((ext_vector_type(2)));
typedef unsigned short u16x2 __attribute__((ext_vector_type(2)));

extern "C" __device__ _Float16 __ocml_exp2_f16(_Float16);

union H4 { ushort4 u; _Float16 h[4]; };
union W8 { f16x8 v; uint32_t w[4]; f16x2 p[4]; };

__device__ inline float fast_exp2(float x) { return __builtin_amdgcn_exp2f(x); }
__device__ inline float fast_rcp(float x) { return __builtin_amdgcn_rcpf(x); }
__device__ inline f32x4 mfma16(f16x8 a, f16x8 b, f32x4 c) {
    return __builtin_amdgcn_mfma_f32_16x16x32_f16(a, b, c, 0, 0, 0);
}
// order-preserving float->uint encode for atomicMax
__device__ inline uint32_t enc_f32(float f) {
    uint32_t u = __float_as_uint(f);
    return (u & 0x80000000u) ? ~u : (u | 0x80000000u);
}
__device__ inline float dec_f32(uint32_t k) {
    uint32_t u = (k & 0x80000000u) ? (k ^ 0x80000000u) : ~k;
    return __uint_as_float(u);
}
// packed f16 {0,1} mask for j-pair k from smeared bits V = rs8 | (rs8<<15)
__device__ inline f16x2 msk01(uint32_t V, int k) {
    uint32_t w = (V >> (2 * k)) & 0x00010001u;
    u16x2 m = __builtin_bit_cast(u16x2, w) * (u16x2){0x3C00, 0x3C00}; // v_pk_mul_lo_u16
    return __builtin_bit_cast(f16x2, m);
}
__device__ inline f16x2 pkmax(f16x2 a, f16x2 b) {
#if __has_builtin(__builtin_elementwise_max)
    return __builtin_elementwise_max(a, b);
#else
    return (f16x2){a[0] > b[0] ? a[0] : b[0], a[1] > b[1] ? a[1] : b[1]};
#endif
}

// ---- fused prep: [0,2048) pack adj->bitsT ; [2048,4096) x->f16 ; [4096,4608) W->wtT ----
__global__ __launch_bounds__(256) void k_prep(const float* __restrict__ x,
                                              const int* __restrict__ adj,
                                              const float* __restrict__ W,
                                              _Float16* __restrict__ xh,
                                              _Float16* __restrict__ wt,
                                              unsigned long long* __restrict__ bitsT,
                                              uint32_t* __restrict__ m4a) {
    const int bid = blockIdx.x;
    if (bid < 2048) {
        // adj int32 {0,1} -> TRANSPOSED bitmask bitsT[m][jw][i] (ull units)
        const long long total = (long long)MM * NN * NN;      // 33554432
        const long long stride = 2048LL * 256;
        long long tid = (long long)bid * 256 + threadIdx.x;
        for (long long e = tid; e < total; e += stride) {
            unsigned long long msk = __ballot(adj[e] != 0);
            if ((threadIdx.x & 63) == 0) {
                long long q = e >> 6;
                int m  = (int)(q >> 18);
                int rem = (int)(q & 262143);
                int i  = rem >> 6;
                int jw = rem & 63;
                bitsT[((size_t)m * 64 + jw) * NN + i] = msk;
            }
        }
    } else if (bid < 4096) {
        int t = (bid - 2048) * 256 + threadIdx.x;  // N*F/4
        if (t < HH) m4a[t] = 0u;                   // encoded floor
        float4 v = ((const float4*)x)[t];
        H4 o;
        o.h[0] = (_Float16)v.x; o.h[1] = (_Float16)v.y;
        o.h[2] = (_Float16)v.z; o.h[3] = (_Float16)v.w;
        ((ushort4*)xh)[t] = o.u;
    } else {
        int t = (bid - 4096) * 256 + threadIdx.x;  // H*F*D
        int c = t >> 9, f = t & 511;
        int h = c >> 6, d = c & 63;
        wt[t] = (_Float16)W[(h * FF + f) * DD + d];
    }
}

// ---- Wh = x @ W[h] -> whT[h*64+d][n] f16 ; fused s1L/s2h/m4a from accumulators ----
__global__ __launch_bounds__(512) void k_wh(const _Float16* __restrict__ xh,
                                            const _Float16* __restrict__ wt,
                                            const float* __restrict__ a1,
                                            const float* __restrict__ a2,
                                            _Float16* __restrict__ whT,
                                            float* __restrict__ s1L,
                                            _Float16* __restrict__ s2h,
                                            uint32_t* __restrict__ m4a) {
    __shared__ float sred[8][2][16];
    const int wave = threadIdx.x >> 6;
    const int h    = wave & 3;
    const int th   = wave >> 2;
    const int lane = threadIdx.x & 63;
    const int iL   = lane & 15;
    const int quad = lane >> 4;
    const int i0   = blockIdx.x * 16;

    f32x4 acc[2];
    acc[0] = (f32x4){0.f, 0.f, 0.f, 0.f};
    acc[1] = (f32x4){0.f, 0.f, 0.f, 0.f};

    const _Float16* arow  = xh + (size_t)(i0 + iL) * FF + quad * 8;
    const _Float16* bbase = wt + (size_t)(h * 64 + th * 32 + iL) * FF + quad * 8;

    for (int kc = 0; kc < FF; kc += 32) {
        f16x8 a = *(const f16x8*)(arow + kc);
        #pragma unroll
        for (int u = 0; u < 2; ++u) {
            f16x8 b = *(const f16x8*)(bbase + (size_t)(16 * u) * FF + kc);
            acc[u] = mfma16(a, b, acc[u]);
        }
    }
    #pragma unroll
    for (int u = 0; u < 2; ++u) {
        H4 o;
        #pragma unroll
        for (int r = 0; r < 4; ++r) o.h[r] = (_Float16)acc[u][r];
        *(ushort4*)(whT + (size_t)(h * 64 + th * 32 + 16 * u + iL) * NN + i0 + quad * 4) = o.u;
    }

    // ---- fused s1/s2: dot over this wave's 32 d's, butterfly over iL, LDS over th ----
    const float a1v0 = a1[h * 64 + th * 32 + iL];
    const float a1v1 = a1[h * 64 + th * 32 + 16 + iL];
    const float a2v0 = a2[h * 64 + th * 32 + iL];
    const float a2v1 = a2[h * 64 + th * 32 + 16 + iL];
    #pragma unroll
    for (int r = 0; r < 4; ++r) {
        float p1 = acc[0][r] * a1v0 + acc[1][r] * a1v1;
        float p2 = acc[0][r] * a2v0 + acc[1][r] * a2v1;
        #pragma unroll
        for (int off = 1; off < 16; off <<= 1) {
            p1 += __shfl_xor(p1, off);
            p2 += __shfl_xor(p2, off);
        }
        if (iL == 0) {
            sred[wave][0][quad * 4 + r] = p1;
            sred[wave][1][quad * 4 + r] = p2;
        }
    }
    __syncthreads();
    if (threadIdx.x < 64) {
        int h2  = threadIdx.x >> 4;
        int idx = threadIdx.x & 15;
        float s1 = sred[h2][0][idx] + sred[h2 + 4][0][idx];
        float s2 = sred[h2][1][idx] + sred[h2 + 4][1][idx];
        float s2l = s2 * LOG2E;
        s1L[h2 * NN + i0 + idx] = s1 * LOG2E;
        s2h[h2 * NN + i0 + idx] = (_Float16)s2l;
        float mx = s2l;
        #pragma unroll
        for (int off = 1; off < 16; off <<= 1) mx = fmaxf(mx, __shfl_xor(mx, off));
        if (idx == 0) atomicMax(m4a + h2, enc_f32(mx));
    }
}

// ---- fused masked-attention + elu + metapath sum ----
// grid 256 = (i-group of 64 rows) x head; 512 thr = 8 waves = 8 j-slices of 512.
// Each wave computes 4 i-subtiles; packed-f16 inner math, bit-smeared masks.
__global__ __launch_bounds__(512, 2) void k_attn(const _Float16* __restrict__ whT,
                                                 const float* __restrict__ s1L,
                                                 const _Float16* __restrict__ s2h,
                                                 const uint32_t* __restrict__ m4a,
                                                 const unsigned long long* __restrict__ bitsT,
                                                 float* __restrict__ out) {
    __shared__ __align__(16) float xr[8][MM][4][16][16]; // [slot][m][t][col][row]
    __shared__ __align__(16) float dr[8][MM][16];

    const int tid  = threadIdx.x;
    const int wave = tid >> 6;
    const int lane = tid & 63;
    const int iL   = lane & 15;
    const int quad = lane >> 4;
    const int h    = blockIdx.x & 3;
    const int i0   = (blockIdx.x >> 2) * 64;      // 64 i-rows per block

    const float m4 = dec_f32(m4a[h]);
    f16x2 A2[4], B2[4];
    #pragma unroll
    for (int s = 0; s < 4; ++s) {
        float s1i = s1L[h * NN + i0 + 16 * s + iL];
        float vv  = s1i + m4;
        float cii = fmaxf(vv, ALPHA_LR * vv);     // lrelu row shift (log2 domain)
        _Float16 a = (_Float16)(s1i - cii);
        _Float16 b = (_Float16)(ALPHA_LR * s1i - cii);
        A2[s] = (f16x2){a, a};
        B2[s] = (f16x2){b, b};
    }
    const f16x2 al2 = (f16x2){(_Float16)ALPHA_LR, (_Float16)ALPHA_LR};

    f32x4 acc[4][MM][4];
    f32x4 accD[4][MM];
    #pragma unroll
    for (int s = 0; s < 4; ++s)
        #pragma unroll
        for (int m = 0; m < MM; ++m) {
            accD[s][m] = (f32x4){0.f, 0.f, 0.f, 0.f};
            #pragma unroll
            for (int t = 0; t < 4; ++t) acc[s][m][t] = (f32x4){0.f, 0.f, 0.f, 0.f};
        }

    f16x8 bones;
    #pragma unroll
    for (int e = 0; e < 8; ++e) bones[e] = (_Float16)1.0f;

    const _Float16* s2row = s2h + h * NN;
    const _Float16* brow = whT + (size_t)(h * 64 + iL) * NN;   // + 16t*NN + j
    const int qshift = quad * 8;
    const int jbase = wave * 512;

    const unsigned long long* pB[MM][4];
    #pragma unroll
    for (int m = 0; m < MM; ++m)
        #pragma unroll
        for (int s = 0; s < 4; ++s)
            pB[m][s] = bitsT + (size_t)m * 64 * NN + i0 + 16 * s + iL;

    for (int it = 0; it < 8; ++it) {
        const int jc = jbase + it * 64;
        const int jw = jc >> 6;
        unsigned long long bm[MM][4];
        #pragma unroll
        for (int m = 0; m < MM; ++m)
            #pragma unroll
            for (int s = 0; s < 4; ++s)
                bm[m][s] = pB[m][s][(size_t)jw * NN];

        #pragma unroll
        for (int half = 0; half < 2; ++half) {
            const int jb = jc + 32 * half;
            // shared b-fragments (amortized over 4 subtiles)
            f16x8 bfr[4];
            #pragma unroll
            for (int t = 0; t < 4; ++t)
                bfr[t] = *(const f16x8*)(brow + (size_t)(16 * t) * NN + jb + qshift);

            const W8 s2v = *(const W8*)(s2row + jb + qshift);  // 8 f16 (4 pairs)
            const int shft = 32 * half + qshift;

            #pragma unroll
            for (int s = 0; s < 4; ++s) {
                uint32_t rs0 = (uint32_t)(bm[0][s] >> shft) & 0xFFu;
                uint32_t rs1 = (uint32_t)(bm[1][s] >> shft) & 0xFFu;
                uint32_t V0 = rs0 | (rs0 << 15);   // bit 2k+1 -> bit 2k+16
                uint32_t V1 = rs1 | (rs1 << 15);
                W8 a0, a1v;
                #pragma unroll
                for (int k = 0; k < 4; ++k) {
                    f16x2 z = s2v.p[k] + A2[s];               // v_pk_add_f16
                    f16x2 l = al2 * s2v.p[k] + B2[s];         // v_pk_fma_f16
                    f16x2 mx = pkmax(z, l);                   // v_pk_max_f16
                    f16x2 p = (f16x2){__ocml_exp2_f16(mx[0]), __ocml_exp2_f16(mx[1])};
                    a0.p[k]  = p * msk01(V0, k);              // v_pk_mul_f16
                    a1v.p[k] = p * msk01(V1, k);
                }
                #pragma unroll
                for (int t = 0; t < 4; ++t) {
                    acc[s][0][t] = mfma16(a0.v, bfr[t], acc[s][0][t]);
                    acc[s][1][t] = mfma16(a1v.v, bfr[t], acc[s][1][t]);
                }
                accD[s][0] = mfma16(a0.v, bones, accD[s][0]);
                accD[s][1] = mfma16(a1v.v, bones, accD[s][1]);
            }
        }
    }

    // ---- epilogue: per s, single 8-slot store + 4-wave finalize (2 syncs/s) ----
    for (int s = 0; s < 4; ++s) {
        __syncthreads();          // previous round's reads complete
        #pragma unroll
        for (int m = 0; m < MM; ++m) {
            #pragma unroll
            for (int t = 0; t < 4; ++t)
                *(f32x4*)&xr[wave][m][t][iL][quad * 4] = acc[s][m][t];
            if (iL == 0) *(f32x4*)&dr[wave][m][quad * 4] = accD[s][m];
        }
        __syncthreads();
        if (wave < 4) {
            const int t = wave;
            f32x4 n0 = (f32x4){0.f, 0.f, 0.f, 0.f};
            f32x4 n1 = (f32x4){0.f, 0.f, 0.f, 0.f};
            f32x4 d0 = (f32x4){0.f, 0.f, 0.f, 0.f};
            f32x4 d1 = (f32x4){0.f, 0.f, 0.f, 0.f};
            #pragma unroll
            for (int sl = 0; sl < 8; ++sl) {
                n0 += *(const f32x4*)&xr[sl][0][t][iL][quad * 4];
                n1 += *(const f32x4*)&xr[sl][1][t][iL][quad * 4];
                d0 += *(const f32x4*)&dr[sl][0][quad * 4];
                d1 += *(const f32x4*)&dr[sl][1][quad * 4];
            }
            const int i0s = i0 + 16 * s;
            #pragma unroll
            for (int r = 0; r < 4; ++r) {
                float v0 = n0[r] * fast_rcp(d0[r]);
                float v1 = n1[r] * fast_rcp(d1[r]);
                float e0 = v0 > 0.f ? v0 : (fast_exp2(v0 * LOG2E) - 1.f);
                float e1 = v1 > 0.f ? v1 : (fast_exp2(v1 * LOG2E) - 1.f);
                out[(size_t)(i0s + quad * 4 + r) * (HH * DD) + h * 64 + 16 * t + iL] = e0 + e1;
            }
        }
    }
}

extern "C" void kernel_launch(void* const* d_in, const int* in_sizes, int n_in,
                              void* d_out, int out_size, void* d_ws, size_t ws_size,
                              hipStream_t stream) {
    const float* x   = (const float*)d_in[0];
    const int*   adj = (const int*)d_in[1];
    const float* W   = (const float*)d_in[2];
    const float* a1  = (const float*)d_in[3];
    const float* a2  = (const float*)d_in[4];
    // d_in[5..7] (Ws, bs, q_sem) mathematically dead: softmax over size-1 axis == 1
    float* out = (float*)d_out;

    char* ws = (char*)d_ws;
    _Float16* xh   = (_Float16*)(ws);                 // 4 MB
    _Float16* wt   = (_Float16*)(ws + 4194304);       // 256 KB
    _Float16* whT  = (_Float16*)(ws + 4456448);       // 2 MB
    float*    s1L  = (float*)(ws + 6553600);          // 64 KB
    _Float16* s2h  = (_Float16*)(ws + 6619136);       // 32 KB
    uint32_t* m4a  = (uint32_t*)(ws + 6684672);       // 16 B
    unsigned long long* bitsT = (unsigned long long*)(ws + 6750208); // 4 MB

    hipLaunchKernelGGL(k_prep, dim3(4608), dim3(256), 0, stream,
                       x, adj, W, xh, wt, bitsT, m4a);
    hipLaunchKernelGGL(k_wh, dim3(256), dim3(512), 0, stream,
                       xh, wt, a1, a2, whT, s1L, s2h, m4a);
    hipLaunchKernelGGL(k_attn, dim3(256), dim3(512), 0, stream,
                       whT, s1L, s2h, m4a, bitsT, out);
}